// Round 7
// baseline (443.235 us; speedup 1.0000x reference)
//
#include <hip/hip_runtime.h>
#include <hip/hip_bf16.h>
#include <float.h>

#define NS 32768
#define KER 256
#define TOUT 32513
#define NATOM 256
#define NSTEP 16
#define BATCH 8
#define NBLK 255
#define XSTR 33024   // NS + 256 pad (zero-filled)
#define SW4(i) ((i) + (((i) >> 5) << 2))

typedef __attribute__((ext_vector_type(8))) _Float16 half8;
typedef __attribute__((ext_vector_type(16))) float f32x16;
typedef __attribute__((ext_vector_type(4))) unsigned int uint4v;

__device__ __forceinline__ void cmax(float& ba, float& bs, float& bi,
                                     float oa, float os, float oi) {
    if (oa > ba || (oa == ba && oi < bi)) { ba = oa; bs = os; bi = oi; }
}

__device__ __forceinline__ void fma8(float acc[8], float4 dA, float4 dB,
                                     float4 w0, float4 w1, float4 w2, float4 w3) {
    float w[16] = {w0.x,w0.y,w0.z,w0.w, w1.x,w1.y,w1.z,w1.w,
                   w2.x,w2.y,w2.z,w2.w, w3.x,w3.y,w3.z,w3.w};
    float dv[8] = {dA.x,dA.y,dA.z,dA.w, dB.x,dB.y,dB.z,dB.w};
#pragma unroll
    for (int i = 0; i < 8; ++i)
#pragma unroll
        for (int j = 0; j < 8; ++j)
            acc[j] = fmaf(dv[i], w[i + j], acc[j]);
}

__device__ __forceinline__ unsigned short f16hi(float v) {
    return __builtin_bit_cast(unsigned short, (_Float16)v);
}
__device__ __forceinline__ unsigned short f16lo(float v) {
    const _Float16 h = (_Float16)v;
    return __builtin_bit_cast(unsigned short, (_Float16)(v - (float)h));
}

// Pre-pack: xh4/xl4[i] = f16 of x[i..i+3] (redundant quads, 8B-aligned b64 reads);
// dhF/dlF[kg*256+atom] = f16 of d[atom][kg*8..kg*8+7] (fragment-major, coalesced).
__global__ __launch_bounds__(256) void k_prep(const float* __restrict__ x,
                                              const float* __restrict__ d,
                                              uint2* __restrict__ xh4,
                                              uint2* __restrict__ xl4,
                                              uint4* __restrict__ dhF,
                                              uint4* __restrict__ dlF) {
    const int gid = blockIdx.x * 256 + threadIdx.x;
    const int NXE = BATCH * XSTR;
    if (gid < NXE) {
        const int b = gid / XSTR, i = gid - b * XSTR;
        float v[4];
#pragma unroll
        for (int u = 0; u < 4; ++u)
            v[u] = (i + u < NS) ? x[b * NS + i + u] : 0.f;
        uint2 hw, lw;
        hw.x = (unsigned int)f16hi(v[0]) | ((unsigned int)f16hi(v[1]) << 16);
        hw.y = (unsigned int)f16hi(v[2]) | ((unsigned int)f16hi(v[3]) << 16);
        lw.x = (unsigned int)f16lo(v[0]) | ((unsigned int)f16lo(v[1]) << 16);
        lw.y = (unsigned int)f16lo(v[2]) | ((unsigned int)f16lo(v[3]) << 16);
        xh4[gid] = hw; xl4[gid] = lw;
    } else {
        const int j = gid - NXE;
        if (j < NATOM * 32) {
            const int kg = j >> 8, atom = j & 255;
            const float* dp = d + atom * 256 + (kg << 3);
            uint4 hw, lw;
            hw.x = (unsigned int)f16hi(dp[0]) | ((unsigned int)f16hi(dp[1]) << 16);
            hw.y = (unsigned int)f16hi(dp[2]) | ((unsigned int)f16hi(dp[3]) << 16);
            hw.z = (unsigned int)f16hi(dp[4]) | ((unsigned int)f16hi(dp[5]) << 16);
            hw.w = (unsigned int)f16hi(dp[6]) | ((unsigned int)f16hi(dp[7]) << 16);
            lw.x = (unsigned int)f16lo(dp[0]) | ((unsigned int)f16lo(dp[1]) << 16);
            lw.y = (unsigned int)f16lo(dp[2]) | ((unsigned int)f16lo(dp[3]) << 16);
            lw.z = (unsigned int)f16lo(dp[4]) | ((unsigned int)f16lo(dp[5]) << 16);
            lw.w = (unsigned int)f16lo(dp[6]) | ((unsigned int)f16lo(dp[7]) << 16);
            dhF[(kg << 8) + atom] = hw;
            dlF[(kg << 8) + atom] = lw;
        }
    }
}

// 32x32x16_f16 MFMA correlation + per-128-block abs-argmax.
// grid (128 t-chunks of 256, 8 atom-groups of 32, 8 b), block 256 (4 waves).
// Wave w: 32 atoms x 64 t (2 n-tiles of 32). Split-f16: hl + lh + hh.
__global__ __launch_bounds__(256) void k_init(const uint2* __restrict__ xh4,
                                              const uint2* __restrict__ xl4,
                                              const uint4* __restrict__ dhF,
                                              const uint4* __restrict__ dlF,
                                              float2* __restrict__ bm) {
    const int c = blockIdx.x, mg = blockIdx.y, b = blockIdx.z;
    const int tid = threadIdx.x;
    const int w = tid >> 6, l = tid & 63;
    const int n = l & 31, h = l >> 5;
    __shared__ uint2 xh[512], xl[512];
    __shared__ float4 wmax[4][32];
    const int t0 = c << 8;
    for (int i = tid; i < 512; i += 256) {
        xh[i] = xh4[b * XSTR + t0 + i];
        xl[i] = xl4[b * XSTR + t0 + i];
    }
    __syncthreads();

    const int arow = (mg << 5) + n;
    f32x16 acc0 = {0.f}, acc1 = {0.f};
#pragma unroll
    for (int j = 0; j < 16; ++j) { acc0[j] = 0.f; acc1[j] = 0.f; }
    const int sb = (w << 6) + n + (h << 3);
#pragma unroll 2
    for (int kk = 0; kk < 16; ++kk) {
        const int kg = (kk << 1) + h;
        const half8 ah = __builtin_bit_cast(half8, dhF[(kg << 8) + arow]);
        const half8 al = __builtin_bit_cast(half8, dlF[(kg << 8) + arow]);
        const int s0 = sb + (kk << 4);
        {
            const uint2 h0 = xh[s0], h1 = xh[s0 + 4];
            const uint2 l0 = xl[s0], l1 = xl[s0 + 4];
            const uint4v hv = {h0.x, h0.y, h1.x, h1.y};
            const uint4v lv = {l0.x, l0.y, l1.x, l1.y};
            const half8 bh = __builtin_bit_cast(half8, hv);
            const half8 bl = __builtin_bit_cast(half8, lv);
            acc0 = __builtin_amdgcn_mfma_f32_32x32x16_f16(ah, bl, acc0, 0, 0, 0);
            acc0 = __builtin_amdgcn_mfma_f32_32x32x16_f16(al, bh, acc0, 0, 0, 0);
            acc0 = __builtin_amdgcn_mfma_f32_32x32x16_f16(ah, bh, acc0, 0, 0, 0);
        }
        {
            const uint2 h0 = xh[s0 + 32], h1 = xh[s0 + 36];
            const uint2 l0 = xl[s0 + 32], l1 = xl[s0 + 36];
            const uint4v hv = {h0.x, h0.y, h1.x, h1.y};
            const uint4v lv = {l0.x, l0.y, l1.x, l1.y};
            const half8 bh = __builtin_bit_cast(half8, hv);
            const half8 bl = __builtin_bit_cast(half8, lv);
            acc1 = __builtin_amdgcn_mfma_f32_32x32x16_f16(ah, bl, acc1, 0, 0, 0);
            acc1 = __builtin_amdgcn_mfma_f32_32x32x16_f16(al, bh, acc1, 0, 0, 0);
            acc1 = __builtin_amdgcn_mfma_f32_32x32x16_f16(ah, bh, acc1, 0, 0, 0);
        }
    }

    // Epilogue: C layout col=lane&31 (t), row=(r&3)+8*(r>>2)+4*h (atom).
    const int tb0 = t0 + (w << 6) + n;
#pragma unroll
    for (int r = 0; r < 16; ++r) {
        const int atom_l = (r & 3) + ((r >> 2) << 3) + (h << 2);
        const float fa = (float)(((mg << 5) + atom_l) * TOUT);
        float ba = -1.f, bsg = 0.f, bi = 3.0e7f;
        const float v0 = acc0[r], v1 = acc1[r];
        if (tb0 < TOUT) { ba = fabsf(v0); bsg = v0; bi = fa + (float)tb0; }
        if (tb0 + 32 < TOUT) {
            const float a1 = fabsf(v1);
            if (a1 > ba) { ba = a1; bsg = v1; bi = fa + (float)(tb0 + 32); }
        }
#pragma unroll
        for (int m = 1; m <= 16; m <<= 1) {
            const float oa = __shfl_xor(ba, m, 32);
            const float os = __shfl_xor(bsg, m, 32);
            const float oi = __shfl_xor(bi, m, 32);
            cmax(ba, bsg, bi, oa, os, oi);
        }
        if (n == 0) wmax[w][atom_l] = make_float4(ba, bsg, bi, 0.f);
    }
    __syncthreads();
    if (tid < 64) {
        const int a = tid & 31, p = tid >> 5;
        const float4 e1 = wmax[(p << 1)][a];
        const float4 e2 = wmax[(p << 1) + 1][a];
        float ba = e1.x, bsg = e1.y, bi = e1.z;
        cmax(ba, bsg, bi, e2.x, e2.y, e2.z);
        const int blk = (c << 1) + p;
        if (blk < NBLK)
            bm[(size_t)((b << 8) + (mg << 5) + a) * NBLK + blk] = make_float2(bsg, bi);
    }
}

// Per-atom (level-2) maxima over all blocks -> l2 buffer 0.
__global__ __launch_bounds__(256) void k_lvl2(const float2* __restrict__ bm,
                                              float4* __restrict__ l2) {
    const int b = blockIdx.y;
    const int oglob = blockIdx.x * 8 + (threadIdx.x >> 5);
    const int lane = threadIdx.x & 31;
    const float2* row = bm + (size_t)(b * NATOM + oglob) * NBLK;
    float ba = -1.f, bsg = 0.f, bi = 3.0e7f;
    for (int i = lane; i < NBLK; i += 32) {
        const float2 e = row[i];
        cmax(ba, bsg, bi, fabsf(e.x), e.x, e.y);
    }
#pragma unroll
    for (int m = 16; m >= 1; m >>= 1) {
        const float oa = __shfl_xor(ba, m, 32);
        const float os = __shfl_xor(bsg, m, 32);
        const float oi = __shfl_xor(bi, m, 32);
        cmax(ba, bsg, bi, oa, os, oi);
    }
    if (lane == 0) l2[(b << 8) + oglob] = make_float4(ba, bsg, bi, 0.f);
}

// One MP step with persistent double-buffered residual:
// select -> copy resid_src slice to resid_dst (applying current subtraction,
// bitwise reference order) -> window correlation update of own 8 atoms.
__global__ __launch_bounds__(512) void k_step(const float* __restrict__ d,
                                              const float* __restrict__ resid_src,
                                              float* __restrict__ resid_dst,
                                              float2* __restrict__ bm,
                                              float4* __restrict__ l2,
                                              int* __restrict__ pos_a,
                                              int* __restrict__ atom_a,
                                              float* __restrict__ amp_a,
                                              int step) {
    const int og = blockIdx.x, b = blockIdx.y;
    const int tid = threadIdx.x;
    const int wave = tid >> 6, lane = tid & 63;
    __shared__ float dt[2048];
    __shared__ float rsu[1024];
    __shared__ float4 sred[8];
    __shared__ float4 upd[8][5];
    __shared__ int sh_pos, sh_atom;
    __shared__ float sh_amp;

    ((float4*)dt)[tid] = ((const float4*)(d + og * 2048))[tid];
    const float4* l2r = l2 + (step & 1) * (BATCH * NATOM);
    float4*       l2w = l2 + ((step + 1) & 1) * (BATCH * NATOM);

    // SELECT(step) — identical in every block
    {
        float ba = -1.f, bsg = 0.f, bi = 3.0e7f;
        if (tid < 256) {
            const float4 e = l2r[(b << 8) + tid];
            ba = e.x; bsg = e.y; bi = e.z;
        }
#pragma unroll
        for (int m = 32; m >= 1; m >>= 1) {
            const float oa = __shfl_xor(ba, m);
            const float os = __shfl_xor(bsg, m);
            const float oi = __shfl_xor(bi, m);
            cmax(ba, bsg, bi, oa, os, oi);
        }
        if (lane == 0) sred[wave] = make_float4(ba, bsg, bi, 0.f);
    }
    __syncthreads();
    if (tid == 0) {
        float4 r = sred[0];
#pragma unroll
        for (int i = 1; i < 8; ++i) {
            const float4 q = sred[i];
            if (q.x > r.x || (q.x == r.x && q.z < r.z)) r = q;
        }
        const int idx = (int)r.z;
        const int atom = idx / TOUT;
        const int pos = idx - atom * TOUT;
        sh_pos = pos; sh_atom = atom; sh_amp = r.y;
        if (og == 0) {
            pos_a[step * BATCH + b] = pos;
            atom_a[step * BATCH + b] = atom;
            amp_a[step * BATCH + b] = r.y;
        }
    }
    __syncthreads();
    const int p = sh_pos, atom_s = sh_atom;
    const float amp = sh_amp;

    // Copy-forward own 1024-sample slice (applying this step's subtraction)
    for (int i = tid; i < 1024; i += 512) {
        const int g = (og << 10) + i;
        float v = resid_src[(size_t)b * NS + g];
        const int off = g - p;
        if (off >= 0 && off < KER)
            v = __fsub_rn(v, __fmul_rn(amp, d[atom_s * KER + off]));
        resid_dst[(size_t)b * NS + g] = v;
    }

    // Build window (resid_src + current subtraction = r_{step+1}, exact order)
    int tlo = p - 255; if (tlo < 0) tlo = 0;
    int thi = p + 255; if (thi > TOUT - 1) thi = TOUT - 1;
    const int bs0 = tlo >> 7, be0 = thi >> 7;
    const int rbase = bs0 << 7;
    const int nblks = be0 - bs0 + 1;
    const int rlen = (nblks << 7) + 255;
    for (int i = tid; i < rlen; i += 512) {
        const int g = rbase + i;
        float v = (g < NS) ? resid_src[(size_t)b * NS + g] : 0.f;
        const int off = g - p;
        if (g < NS && off >= 0 && off < KER)
            v = __fsub_rn(v, __fmul_rn(amp, d[atom_s * KER + off]));
        rsu[SW4(i)] = v;
    }
    __syncthreads();

    // Recompute bm for own 8 atoms over affected blocks (4-way K-split per wave)
    const int lg = lane >> 4, l16 = lane & 15;
    const float* dp = dt + (wave << 8) + (lg << 6);
    const int atomg = (og << 3) + wave;
    for (int bb = 0; bb < nblks; ++bb) {
        const int blk = bs0 + bb;
        const int t0r = (bb << 7) + (l16 << 3) + (lg << 6);
        float acc[8];
#pragma unroll
        for (int j = 0; j < 8; ++j) acc[j] = 0.f;
        float4 A0 = *(const float4*)(rsu + SW4(t0r));
        float4 A1 = *(const float4*)(rsu + SW4(t0r + 4));
        float4 B0 = *(const float4*)(rsu + SW4(t0r + 8));
        float4 B1 = *(const float4*)(rsu + SW4(t0r + 12));
#pragma unroll
        for (int kk = 0; kk < 64; kk += 16) {
            const float4 d0 = *(const float4*)(dp + kk);
            const float4 d1 = *(const float4*)(dp + kk + 4);
            const float4 N0 = *(const float4*)(rsu + SW4(t0r + kk + 16));
            const float4 N1 = *(const float4*)(rsu + SW4(t0r + kk + 20));
            fma8(acc, d0, d1, A0, A1, B0, B1);
            const float4 d2 = *(const float4*)(dp + kk + 8);
            const float4 d3 = *(const float4*)(dp + kk + 12);
            const float4 M0 = *(const float4*)(rsu + SW4(t0r + kk + 24));
            const float4 M1 = *(const float4*)(rsu + SW4(t0r + kk + 28));
            fma8(acc, d2, d3, B0, B1, N0, N1);
            A0 = N0; A1 = N1; B0 = M0; B1 = M1;
        }
#pragma unroll
        for (int j = 0; j < 8; ++j) {
            acc[j] += __shfl_xor(acc[j], 16);
            acc[j] += __shfl_xor(acc[j], 32);
        }
        float ba = -1.f, bsg = 0.f, bi = 3.0e7f;
        const int tbp = rbase + (bb << 7) + (l16 << 3);
#pragma unroll
        for (int j = 0; j < 8; ++j) {
            const int t = tbp + j;
            const float av = fabsf(acc[j]);
            if (t < TOUT && av > ba) { ba = av; bsg = acc[j]; bi = (float)(atomg * TOUT + t); }
        }
#pragma unroll
        for (int m = 32; m >= 1; m >>= 1) {
            const float oa = __shfl_xor(ba, m);
            const float os = __shfl_xor(bsg, m);
            const float oi = __shfl_xor(bi, m);
            cmax(ba, bsg, bi, oa, os, oi);
        }
        if (lane == 0) {
            bm[(size_t)(b * NATOM + atomg) * NBLK + blk] = make_float2(bsg, bi);
            upd[wave][bb] = make_float4(ba, bsg, bi, 0.f);
        }
    }
    __syncthreads();

    // l2 refresh (global row, LDS-override for just-updated blocks)
    {
        float ba = -1.f, bsg = 0.f, bi = 3.0e7f;
        const float2* row = bm + (size_t)(b * NATOM + atomg) * NBLK;
        for (int i = lane; i < NBLK; i += 64) {
            if (i >= bs0 && i <= be0) {
                const float4 e2 = upd[wave][i - bs0];
                cmax(ba, bsg, bi, e2.x, e2.y, e2.z);
            } else {
                const float2 e2 = row[i];
                cmax(ba, bsg, bi, fabsf(e2.x), e2.x, e2.y);
            }
        }
#pragma unroll
        for (int m = 32; m >= 1; m >>= 1) {
            const float oa = __shfl_xor(ba, m);
            const float os = __shfl_xor(bsg, m);
            const float oi = __shfl_xor(bi, m);
            cmax(ba, bsg, bi, oa, os, oi);
        }
        if (lane == 0) l2w[(b << 8) + atomg] = make_float4(ba, bsg, bi, 0.f);
    }
}

// Head; blocks with s==15 compute the final select inline from l2 parity buf.
__global__ __launch_bounds__(128) void k_head(const int* __restrict__ pos_a,
                                              const int* __restrict__ atom_a,
                                              const float* __restrict__ amp_a,
                                              const float4* __restrict__ l2,
                                              const float* __restrict__ wpa,
                                              const float* __restrict__ bpa,
                                              const float* __restrict__ wat,
                                              const float* __restrict__ bat,
                                              const float* __restrict__ wr,
                                              const float* __restrict__ br,
                                              float* __restrict__ out) {
    const int s = blockIdx.x, b = blockIdx.y;
    const int o = threadIdx.x;
    __shared__ float4 hred[2];
    __shared__ int sh_pos, sh_atom;
    __shared__ float sh_amp;
    int pos, atom; float amp;
    if (s == NSTEP - 1) {
        const float4* l2r = l2 + ((NSTEP - 1) & 1) * (BATCH * NATOM);
        float ba = -1.f, bsg = 0.f, bi = 3.0e7f;
        const float4 e0 = l2r[(b << 8) + o];
        const float4 e1 = l2r[(b << 8) + 128 + o];
        cmax(ba, bsg, bi, e0.x, e0.y, e0.z);
        cmax(ba, bsg, bi, e1.x, e1.y, e1.z);
#pragma unroll
        for (int m = 32; m >= 1; m >>= 1) {
            const float oa = __shfl_xor(ba, m);
            const float os = __shfl_xor(bsg, m);
            const float oi = __shfl_xor(bi, m);
            cmax(ba, bsg, bi, oa, os, oi);
        }
        if ((o & 63) == 0) hred[o >> 6] = make_float4(ba, bsg, bi, 0.f);
        __syncthreads();
        if (o == 0) {
            float4 r = hred[0];
            const float4 q = hred[1];
            if (q.x > r.x || (q.x == r.x && q.z < r.z)) r = q;
            const int idx = (int)r.z;
            sh_atom = idx / TOUT;
            sh_pos = idx - sh_atom * TOUT;
            sh_amp = r.y;
        }
        __syncthreads();
        pos = sh_pos; atom = sh_atom; amp = sh_amp;
    } else {
        pos  = pos_a[s * BATCH + b];
        atom = atom_a[s * BATCH + b];
        amp  = amp_a[s * BATCH + b];
    }
    const float posn = (float)pos / 32513.0f;
    float sum = br[o];
    for (int c = 0; c < 128; ++c) {
        const float pa = wpa[c * 2] * posn + wpa[c * 2 + 1] * amp + bpa[c];
        const float at = wat[c * 256 + atom] + bat[c];
        sum += wr[o * 256 + c] * pa + wr[o * 256 + 128 + c] * at;
    }
    out[(b * 128 + o) * NSTEP + s] = sum;
}

extern "C" void kernel_launch(void* const* d_in, const int* in_sizes, int n_in,
                              void* d_out, int out_size, void* d_ws, size_t ws_size,
                              hipStream_t stream) {
    const float* x   = (const float*)d_in[0];
    const float* d   = (const float*)d_in[1];
    const float* wpa = (const float*)d_in[2];
    const float* bpa = (const float*)d_in[3];
    const float* wat = (const float*)d_in[4];
    const float* bat = (const float*)d_in[5];
    const float* wr  = (const float*)d_in[6];
    const float* br  = (const float*)d_in[7];
    float* out = (float*)d_out;

    char* ws = (char*)d_ws;
    float2* bm     = (float2*)ws;                                   // 4,177,920
    float4* l2     = (float4*)(ws + 4177920);                       // 65,536
    int*    pos_a  = (int*)(ws + 4243456);                          // 512
    int*    atom_a = (int*)(ws + 4243968);                          // 512
    float*  amp_a  = (float*)(ws + 4244480);                        // 512
    float*  resid0 = (float*)(ws + 4244992);                        // 1,048,576
    float*  resid1 = (float*)(ws + 5293568);                        // 1,048,576
    uint2*  xh4    = (uint2*)(ws + 6342144);                        // 2,113,536
    uint2*  xl4    = (uint2*)(ws + 8455680);                        // 2,113,536
    uint4*  dhF    = (uint4*)(ws + 10569216);                       // 131,072
    uint4*  dlF    = (uint4*)(ws + 10700288);                       // 131,072

    hipMemcpyAsync(resid0, x, (size_t)BATCH * NS * sizeof(float),
                   hipMemcpyDeviceToDevice, stream);
    const int prep_n = BATCH * XSTR + NATOM * 32;
    k_prep<<<(prep_n + 255) / 256, 256, 0, stream>>>(x, d, xh4, xl4, dhF, dlF);
    k_init<<<dim3(128, 8, 8), 256, 0, stream>>>(xh4, xl4, dhF, dlF, bm);
    k_lvl2<<<dim3(32, 8), 256, 0, stream>>>(bm, l2);
    for (int st = 0; st < NSTEP - 1; ++st) {
        float* rs = (st & 1) ? resid1 : resid0;
        float* rd = (st & 1) ? resid0 : resid1;
        k_step<<<dim3(32, 8), 512, 0, stream>>>(d, rs, rd, bm, l2,
                                                pos_a, atom_a, amp_a, st);
    }
    k_head<<<dim3(16, 8), 128, 0, stream>>>(pos_a, atom_a, amp_a, l2,
                                            wpa, bpa, wat, bat, wr, br, out);
}